// Round 8
// baseline (292.555 us; speedup 1.0000x reference)
//
#include <hip/hip_runtime.h>
#include <stdint.h>

#define M_DIM 2048
#define N_DIM 4096
#define K_DIM 4096
#define NGROUP 32
#define GSIZE 128

#define RQ_UP   (127.0f / 15.0f)   // weight requant gain
#define RQ_DOWN (15.0f / 127.0f)

// ---------------------------------------------------------------------------
// R8: (a) k-tiled pre-swizzled global layout for A8/Bt8 — every gl2lds now
// reads 1024 CONTIGUOUS bytes (R0-R7 all gathered 16 scattered 64B segments
// per DMA instr; R3 proved that pattern catastrophic for reg-loads). prep
// writes tiles [mt/nt][kt][128 rows][64B-swizzled], so the GEMM's LDS image
// is byte-identical to R6's — ds_read/MFMA/epilogue are untouched.
// (b) diagnostic probes (template MODE): 1=MFMA-only, 2=memory-only,
// plus a grid-16 full probe. Launched BEFORE the real gemm; real gemm
// overwrites out completely -> correctness preserved. Probe REPS=2 to stay
// in rocprof's top-5.
// Geometry = R6 (best measured): 128x128 tile, 4 waves 2Mx2N, wave 64x64 =
// 4x4 frags of 16x16x64 i8 MFMA, 4 LDS slots, distance-3 prefetch, 2
// blocks/CU, reg-dbuf frags, counted vmcnt(8)/lgkmcnt(8).
// ---------------------------------------------------------------------------
#define BM 128
#define BN 128
#define KSLICE 64
#define NSLICE (K_DIM / KSLICE)    // 64
#define ASLOT (BM * KSLICE)        //  8 KiB
#define BSLOT (BN * KSLICE)        //  8 KiB

typedef __attribute__((ext_vector_type(4))) int int32x4_t;

static __device__ __forceinline__ void gl2lds16(const void* g, void* l) {
    auto gp = (const __attribute__((address_space(1))) unsigned int*)(uintptr_t)g;
    auto lp = (__attribute__((address_space(3))) unsigned int*)(uintptr_t)l;
    __builtin_amdgcn_global_load_lds(gp, lp, 16, 0, 0);
}

#define WAITVM_(N) asm volatile("s_waitcnt vmcnt(" #N ")")
#define WAITVM(N)                                   \
    do {                                            \
        __builtin_amdgcn_sched_barrier(0);          \
        WAITVM_(N);                                 \
        __builtin_amdgcn_sched_barrier(0);          \
    } while (0)
#define WAITLGKM_(N) asm volatile("s_waitcnt lgkmcnt(" #N ")")
#define WAITLGKM(N)                                 \
    do {                                            \
        __builtin_amdgcn_sched_barrier(0);          \
        WAITLGKM_(N);                               \
        __builtin_amdgcn_sched_barrier(0);          \
    } while (0)
#define BARRIER()                                   \
    do {                                            \
        __builtin_amdgcn_sched_barrier(0);          \
        __builtin_amdgcn_s_barrier();               \
        __builtin_amdgcn_sched_barrier(0);          \
    } while (0)

// ---------------------------------------------------------------------------
// Fused prep. NEW: A8/Bt8 written k-tiled+swizzled:
//   tile (rt, kt) at ((rt*64 + kt) * 8192); inside: row r (=m&127 / n&127)
//   at r*64; 16B chunk c of the 64B k-slice stored at slot c ^ ((r>>1)&3).
// Same store widths/counts as before -> prep cost unchanged.
// ---------------------------------------------------------------------------
#define QUANT_BLOCKS M_DIM
#define DEQ_BLOCKS ((N_DIM * K_DIM) / 8 / 256)       // 8 codes / thread

__global__ __launch_bounds__(256) void prep_kernel(
        const float* __restrict__ x,
        const int* __restrict__ qw,          // [N][K] codes 0..15 as int32
        const float* __restrict__ wsc,       // [N][32]
        const int* __restrict__ wzp,         // [N][32]
        char* __restrict__ A8,               // tiled [16][64][128][64]
        char* __restrict__ Bt8,              // tiled [32][64][128][64]
        float* __restrict__ xscale,          // [M]
        float* __restrict__ xzpc,            // [M]  = 128 - zp
        int* __restrict__ Sw)                // [N][32] group sums of Bt8
{
    const int t = threadIdx.x;
    if (blockIdx.x < QUANT_BLOCKS) {
        const int s = blockIdx.x;
        const float* xrow = x + (size_t)s * K_DIM;

        float xv[16];
        float vmin = 1e38f, vmax = -1e38f;
#pragma unroll
        for (int p = 0; p < 4; ++p) {
            float4 v = *((const float4*)(xrow + p * 1024) + t);
            xv[p*4+0] = v.x; xv[p*4+1] = v.y; xv[p*4+2] = v.z; xv[p*4+3] = v.w;
            vmin = fminf(vmin, fminf(fminf(v.x, v.y), fminf(v.z, v.w)));
            vmax = fmaxf(vmax, fmaxf(fmaxf(v.x, v.y), fmaxf(v.z, v.w)));
        }
#pragma unroll
        for (int off = 32; off > 0; off >>= 1) {
            vmin = fminf(vmin, __shfl_xor(vmin, off));
            vmax = fmaxf(vmax, __shfl_xor(vmax, off));
        }
        __shared__ float smin[4], smax[4];
        const int wave = t >> 6;
        if ((t & 63) == 0) { smin[wave] = vmin; smax[wave] = vmax; }
        __syncthreads();
        vmin = fminf(fminf(smin[0], smin[1]), fminf(smin[2], smin[3]));
        vmax = fmaxf(fmaxf(smax[0], smax[1]), fmaxf(smax[2], smax[3]));

        float sc = (vmax - vmin) / 255.0f;
        sc = fmaxf(sc, 1e-5f);
        float zp = rintf(-vmin / sc);
        zp = fminf(fmaxf(zp, 0.0f), 255.0f);
        const float inv_sc = 1.0f / sc;

        const int r   = s & 127;
        const int mt  = s >> 7;
        const int swr = (r >> 1) & 3;
#pragma unroll
        for (int p = 0; p < 4; ++p) {
            int b[4];
#pragma unroll
            for (int e = 0; e < 4; ++e) {
                float q = fminf(fmaxf(rintf(xv[p*4+e] * inv_sc) + zp, 0.0f), 255.0f);
                b[e] = (int)q - 128;
            }
            unsigned pack = (b[0] & 0xff) | ((b[1] & 0xff) << 8) |
                            ((b[2] & 0xff) << 16) | ((b[3] & 0xff) << 24);
            const int kt   = p * 16 + (t >> 4);
            const int slot = ((t >> 2) & 3) ^ swr;
            *(unsigned*)(A8 + (((size_t)(mt * 64 + kt)) << 13)
                            + r * 64 + slot * 16 + (t & 3) * 4) = pack;
        }
        if (t == 0) { xscale[s] = sc; xzpc[s] = 128.0f - zp; }
    } else {
        // ---- weight requant: 8 codes/thread; 16-lane cluster = 1 group ----
        const size_t base = ((size_t)(blockIdx.x - QUANT_BLOCKS) * 256 + t) * 8;
        const int n = (int)(base >> 12);          // /4096
        const int g = (int)((base >> 7) & 31);
        const int zp = wzp[n * NGROUP + g];

        // inline rsn: row max of the 32 scales across the 16-lane cluster
        const int cl = t & 15;
        float2 wp = *(const float2*)(wsc + (size_t)n * NGROUP + cl * 2);
        float smx = fmaxf(wp.x, wp.y);
#pragma unroll
        for (int off = 1; off < 16; off <<= 1)
            smx = fmaxf(smx, __shfl_xor(smx, off));
        const float factor = wsc[n * NGROUP + g] * (RQ_UP / smx);   // <= 127/15

        int4 c0 = *(const int4*)(qw + base);
        int4 c1 = *(const int4*)(qw + base + 4);
        int w[8];
        w[0] = (int)rintf((float)(c0.x - zp) * factor);
        w[1] = (int)rintf((float)(c0.y - zp) * factor);
        w[2] = (int)rintf((float)(c0.z - zp) * factor);
        w[3] = (int)rintf((float)(c0.w - zp) * factor);
        w[4] = (int)rintf((float)(c1.x - zp) * factor);
        w[5] = (int)rintf((float)(c1.y - zp) * factor);
        w[6] = (int)rintf((float)(c1.z - zp) * factor);
        w[7] = (int)rintf((float)(c1.w - zp) * factor);
        uint2 pk;
        pk.x = (w[0] & 0xff) | ((w[1] & 0xff) << 8) | ((w[2] & 0xff) << 16) | ((w[3] & 0xff) << 24);
        pk.y = (w[4] & 0xff) | ((w[5] & 0xff) << 8) | ((w[6] & 0xff) << 16) | ((w[7] & 0xff) << 24);

        const int r  = n & 127;
        const int nt = n >> 7;
        const int kt = (int)((base >> 6) & 63);
        const int slot = (int)(((base >> 4) & 3)) ^ ((r >> 1) & 3);
        *(uint2*)(Bt8 + (((size_t)(nt * 64 + kt)) << 13)
                      + r * 64 + slot * 16 + (int)(base & 15)) = pk;

        int s8 = w[0] + w[1] + w[2] + w[3] + w[4] + w[5] + w[6] + w[7];
#pragma unroll
        for (int off = 1; off < 16; off <<= 1) s8 += __shfl_xor(s8, off);
        if ((t & 15) == 0)
            Sw[n * NGROUP + g] = s8;     // coalesced, no atomic
    }
}

// ---------------------------------------------------------------------------
// Pipelined i8 GEMM (R6 schedule, tiled-contiguous staging).
// MODE 0 = real; 1 = MFMA-only probe; 2 = memory-only probe.
// ---------------------------------------------------------------------------
template<int MODE, int REPS>
__global__ __launch_bounds__(256, 2) void gemm_kernel(
        const char* __restrict__ A8,     // tiled
        const char* __restrict__ Bt8,    // tiled
        const float* __restrict__ xscale,
        const float* __restrict__ xzpc,
        const float* __restrict__ wsc,   // [N][32]
        const int* __restrict__ Sw,      // [N][32]
        const float* __restrict__ bias,  // [N]
        float* __restrict__ out)         // [M][N] f32
{
    __shared__ __align__(16) char As[4][ASLOT];   // 32 KiB
    __shared__ __align__(16) char Bs[4][BSLOT];   // 32 KiB
    __shared__ float fws_s[BN], wsf_s[BN];
    // keep LDS allocated in MODE 1 (occupancy parity across probes)
    asm volatile("" :: "s"((unsigned)(uintptr_t)&As[0][0]),
                       "s"((unsigned)(uintptr_t)&Bs[0][0]));

    const int tid  = threadIdx.x;
    const int bn   = blockIdx.x;
    const int bm   = blockIdx.y;
    const int wave = tid >> 6;           // 0..3
    const int lane = tid & 63;
    const int wr   = wave >> 1;          // 0..1 -> 64-row band
    const int wcl  = wave & 1;           // 0..1 -> 64-col band
    const int lrow  = lane & 15;
    const int lquad = lane >> 4;         // 0..3 -> 16B k-chunk

    // --- per-column epilogue constants ---
    if (tid < BN) {
        const int n = bn * BN + tid;
        const int4* s4 = (const int4*)(Sw + (size_t)n * NGROUP);
        int acc = 0;
#pragma unroll
        for (int p = 0; p < 8; ++p) { int4 v = s4[p]; acc += v.x + v.y + v.z + v.w; }
        const float4* w4 = (const float4*)(wsc + (size_t)n * NGROUP);
        float s = 0.f;
#pragma unroll
        for (int p = 0; p < 8; ++p) {
            float4 w = w4[p];
            s = fmaxf(s, fmaxf(fmaxf(w.x, w.y), fmaxf(w.z, w.w)));
        }
        const float fw = s * RQ_DOWN;
        fws_s[tid] = fw;
        wsf_s[tid] = fw * (float)acc;
    }
    __builtin_amdgcn_sched_barrier(0);
    asm volatile("s_waitcnt vmcnt(0) lgkmcnt(0)");
    __builtin_amdgcn_sched_barrier(0);

    // --- staging sources: tile (bm|bn, kt) is 8 KiB CONTIGUOUS, already
    // swizzle-ordered by prep. Per slice: 2 instr/wave each 1024 B. ---
    const char* srcA = A8  + ((size_t)bm << 19) + wave * 1024 + lane * 16;
    const char* srcB = Bt8 + ((size_t)bn << 19) + wave * 1024 + lane * 16;
    const int lOF = wave * 1024;

    // --- ds_read addresses (LDS image identical to R6) ---
    const int xq = (lquad ^ ((lrow >> 1) & 3)) * 16;
    const unsigned asBase = (unsigned)(uintptr_t)&As[0][0];
    const unsigned bsBase = (unsigned)(uintptr_t)&Bs[0][0];
    const unsigned aOff0 = (unsigned)((wr  * 64 + lrow) * KSLICE + xq);
    const unsigned bOff0 = (unsigned)((wcl * 64 + lrow) * KSLICE + xq);

    int32x4_t iacc[4][4];
    const int32x4_t zi = {0, 0, 0, 0};
#pragma unroll
    for (int i = 0; i < 4; ++i)
#pragma unroll
        for (int j = 0; j < 4; ++j) iacc[i][j] = zi;

#define STAGE(t) {                                                    \
        const int sl_ = (t) & 3;                                      \
        const size_t o_ = (size_t)(t) << 13;                          \
        gl2lds16(srcA + o_,        &As[sl_][0] + lOF);                \
        gl2lds16(srcA + o_ + 4096, &As[sl_][0] + 4096 + lOF);         \
        gl2lds16(srcB + o_,        &Bs[sl_][0] + lOF);                \
        gl2lds16(srcB + o_ + 4096, &Bs[sl_][0] + 4096 + lOF);         \
    }

#define READ8(aAdr, bAdr, a0, a1, a2, a3, b0, b1, b2, b3)             \
    asm volatile(                                                     \
        "ds_read_b128 %0, %8 offset:0\n\t"                            \
        "ds_read_b128 %1, %8 offset:1024\n\t"                         \
        "ds_read_b128 %2, %8 offset:2048\n\t"                         \
        "ds_read_b128 %3, %8 offset:3072\n\t"                         \
        "ds_read_b128 %4, %9 offset:0\n\t"                            \
        "ds_read_b128 %5, %9 offset:1024\n\t"                         \
        "ds_read_b128 %6, %9 offset:2048\n\t"                         \
        "ds_read_b128 %7, %9 offset:3072"                             \
        : "=&v"(a0), "=&v"(a1), "=&v"(a2), "=&v"(a3),                 \
          "=&v"(b0), "=&v"(b1), "=&v"(b2), "=&v"(b3)                  \
        : "v"(aAdr), "v"(bAdr))

#define READF(s, A0,A1,A2,A3,B0,B1,B2,B3) {                           \
        const unsigned sl_ = (unsigned)((s) & 3) * 8192u;             \
        READ8(asBase + sl_ + aOff0, bsBase + sl_ + bOff0,             \
              A0, A1, A2, A3, B0, B1, B2, B3);                        \
    }

#define MFMAS(a0, a1, a2, a3, b0, b1, b2, b3) {                       \
        int32x4_t av_[4] = {a0, a1, a2, a3};                          \
        int32x4_t bv_[4] = {b0, b1, b2, b3};                          \
        __builtin_amdgcn_s_setprio(1);                                \
        _Pragma("unroll")                                             \
        for (int i_ = 0; i_ < 4; ++i_)                                \
            _Pragma("unroll")                                         \
            for (int j_ = 0; j_ < 4; ++j_)                            \
                iacc[i_][j_] = __builtin_amdgcn_mfma_i32_16x16x64_i8( \
                    av_[i_], bv_[j_], iacc[i_][j_], 0, 0, 0);         \
        __builtin_amdgcn_s_setprio(0);                                \
    }

#define KEEPA(a0, a1, a2, a3, b0, b1, b2, b3)                         \
    asm volatile("" :: "v"(a0), "v"(a1), "v"(a2), "v"(a3),            \
                       "v"(b0), "v"(b1), "v"(b2), "v"(b3))

    int32x4_t aA0, aA1, aA2, aA3, bA0, bA1, bA2, bA3;   // set A
    int32x4_t aB0, aB1, aB2, aB3, bB0, bB1, bB2, bB3;   // set B

#define BODY(s, VMN, DOSTAGE, CA0,CA1,CA2,CA3,CB0,CB1,CB2,CB3,        \
             NA0,NA1,NA2,NA3,NB0,NB1,NB2,NB3) {                       \
        if constexpr (MODE != 1) {                                    \
            if (DOSTAGE) STAGE((s) + 3);                              \
            WAITVM(VMN);                                              \
        }                                                             \
        BARRIER();                                                    \
        if constexpr (MODE != 1) {                                    \
            READF((s) + 1, NA0,NA1,NA2,NA3,NB0,NB1,NB2,NB3);          \
            WAITLGKM(8);                                              \
        }                                                             \
        if constexpr (MODE != 2) {                                    \
            MFMAS(CA0,CA1,CA2,CA3,CB0,CB1,CB2,CB3);                   \
        } else {                                                      \
            KEEPA(NA0,NA1,NA2,NA3,NB0,NB1,NB2,NB3);                   \
        }                                                             \
        BARRIER();                                                    \
    }

    for (int rep = 0; rep < REPS; ++rep) {
        // ---- prologue ----
        if constexpr (MODE != 1) {
            STAGE(0); STAGE(1); STAGE(2);
            WAITVM(8);
            BARRIER();
            READF(0, aA0,aA1,aA2,aA3,bA0,bA1,bA2,bA3);
        } else {
            BARRIER();
            asm volatile("" : "=v"(aA0), "=v"(aA1), "=v"(aA2), "=v"(aA3),
                              "=v"(bA0), "=v"(bA1), "=v"(bA2), "=v"(bA3));
            asm volatile("" : "=v"(aB0), "=v"(aB1), "=v"(aB2), "=v"(aB3),
                              "=v"(bB0), "=v"(bB1), "=v"(bB2), "=v"(bB3));
        }

        // ---- steady state: bodies 0..59 in even/odd pairs ----
        for (int s = 0; s < NSLICE - 4; s += 2) {
            BODY(s,     8, 1, aA0,aA1,aA2,aA3,bA0,bA1,bA2,bA3,
                              aB0,aB1,aB2,aB3,bB0,bB1,bB2,bB3);
            BODY(s + 1, 8, 1, aB0,aB1,aB2,aB3,bB0,bB1,bB2,bB3,
                              aA0,aA1,aA2,aA3,bA0,bA1,bA2,bA3);
        }
        // ---- tail: bodies 60..63 ----
        BODY(60, 8, 1, aA0,aA1,aA2,aA3,bA0,bA1,bA2,bA3,
                       aB0,aB1,aB2,aB3,bB0,bB1,bB2,bB3);
        BODY(61, 4, 0, aB0,aB1,aB2,aB3,bB0,bB1,bB2,bB3,
                       aA0,aA1,aA2,aA3,bA0,bA1,bA2,bA3);
        // body 62
        if constexpr (MODE != 1) WAITVM(0);
        BARRIER();
        if constexpr (MODE != 1) {
            READF(63, aB0,aB1,aB2,aB3,bB0,bB1,bB2,bB3);
            WAITLGKM(8);
        }
        if constexpr (MODE != 2) {
            MFMAS(aA0,aA1,aA2,aA3,bA0,bA1,bA2,bA3);
        } else {
            KEEPA(aB0,aB1,aB2,aB3,bB0,bB1,bB2,bB3);
        }
        // body 63
        if constexpr (MODE != 1) WAITLGKM(0);
        if constexpr (MODE != 2) {
            MFMAS(aB0,aB1,aB2,aB3,bB0,bB1,bB2,bB3);
        } else {
            KEEPA(aB0,aB1,aB2,aB3,bB0,bB1,bB2,bB3);
        }
        BARRIER();   // rep boundary
    }

    // --- epilogue: C/D layout col=lane&15, row=lquad*4+reg ---
    float fn[4], wf[4], bb[4];
    int ncol[4];
#pragma unroll
    for (int j = 0; j < 4; ++j) {
        const int ncl = wcl * 64 + j * 16 + lrow;
        ncol[j] = bn * BN + ncl;
        fn[j] = fws_s[ncl];
        wf[j] = wsf_s[ncl];
        bb[j] = bias[ncol[j]];
    }
    const int m0 = bm * BM + wr * 64;
#pragma unroll
    for (int i = 0; i < 4; ++i) {
#pragma unroll
        for (int r = 0; r < 4; ++r) {
            const int m = m0 + i * 16 + lquad * 4 + r;
            const float xs  = xscale[m];
            const float czp = xzpc[m];
            float* orow = out + (size_t)m * N_DIM;
#pragma unroll
            for (int j = 0; j < 4; ++j)
                orow[ncol[j]] = xs * (fn[j] * (float)iacc[i][j][r] + czp * wf[j]) + bb[j];
        }
    }
#undef BODY
#undef KEEPA
#undef MFMAS
#undef READF
#undef READ8
#undef STAGE
}

extern "C" void kernel_launch(void* const* d_in, const int* in_sizes, int n_in,
                              void* d_out, int out_size, void* d_ws, size_t ws_size,
                              hipStream_t stream) {
    const float* x     = (const float*)d_in[0];
    const int*   qw    = (const int*)d_in[1];
    const float* wsc   = (const float*)d_in[2];
    const int*   wzp   = (const int*)d_in[3];
    const float* bias  = (const float*)d_in[4];
    float* out = (float*)d_out;

    // workspace layout
    char* A8  = (char*)d_ws;                                   //  8 MiB (tiled)
    char* Bt8 = A8 + (size_t)M_DIM * K_DIM;                    // 16 MiB (tiled)
    float* xscale = (float*)(Bt8 + (size_t)N_DIM * K_DIM);     //  8 KiB
    float* xzpc   = xscale + M_DIM;                            //  8 KiB
    int*   Sw     = (int*)(xzpc + M_DIM);                      // 512 KiB

    prep_kernel<<<QUANT_BLOCKS + DEQ_BLOCKS, 256, 0, stream>>>(
        x, qw, wsc, wzp, A8, Bt8, xscale, xzpc, Sw);

    dim3 grid(N_DIM / BN, M_DIM / BM);                          // 32 x 16
    // --- probes (outputs overwritten by the real gemm below) ---
    gemm_kernel<1, 2><<<grid, 256, 0, stream>>>(                // D3: MFMA-only
        A8, Bt8, xscale, xzpc, wsc, Sw, bias, out);
    gemm_kernel<2, 2><<<grid, 256, 0, stream>>>(                // D4: memory-only
        A8, Bt8, xscale, xzpc, wsc, Sw, bias, out);
    gemm_kernel<0, 2><<<dim3(4, 4), 256, 0, stream>>>(          // D2: grid-16 full
        A8, Bt8, xscale, xzpc, wsc, Sw, bias, out);
    // --- real gemm ---
    gemm_kernel<0, 1><<<grid, 256, 0, stream>>>(
        A8, Bt8, xscale, xzpc, wsc, Sw, bias, out);
}

// Round 9
// 172.987 us; speedup vs baseline: 1.6912x; 1.6912x over previous
//
#include <hip/hip_runtime.h>
#include <stdint.h>

#define M_DIM 2048
#define N_DIM 4096
#define K_DIM 4096
#define NGROUP 32
#define GSIZE 128

#define RQ_UP   (127.0f / 15.0f)   // weight requant gain
#define RQ_DOWN (15.0f / 127.0f)

// ---------------------------------------------------------------------------
// R9: ZERO-LDS GEMM. R8's probes proved the wall: memory-phase alone (no
// MFMA) = 26.2 µs at full grid, and the barriered schedule phase-locks the
// two co-resident blocks so LDS-phase and MFMA-phase serialize (full ≈
// memory + MFMA + barrier overhead ≈ 50 µs, stable across R0-R7 variants).
// Fix: drop LDS/barriers from the K-loop entirely. The R8 k-tiled global
// layout makes each wave's fragments a contiguous coalescible region ->
// load DIRECTLY global->VGPR (12x dwordx4 = 1 KiB each per slice), register
// double-buffered, per-wave counted waits emitted by the compiler (its
// register-load scheduling is the proven-good path). Waves free-run; vmem
// drains under the 653-cyc MFMA window. L1/L2 absorb the 2x wave-pair
// duplication. Block 128x256, 4 waves 2Mx2N, wave 64x128 = 4x8 frags of
// 16x16x64 i8 MFMA. Grid 16x16 = 1 block/CU, 1 wave/SIMD, 512-reg budget.
// ---------------------------------------------------------------------------
#define BM 128
#define BN 256
#define NSLICE (K_DIM / 64)        // 64

typedef __attribute__((ext_vector_type(4))) int int32x4_t;

// ---------------------------------------------------------------------------
// Fused prep (identical to R8 — verified bit-exact via absmax):
//   [0, 2048): per-token activation quant -> A8 tiled, xscale, czp
//   [2048, ..): weight requant -> Bt8 tiled + group sums Sw.
// Tiled layout: tile (rt, kt) at ((rt*64 + kt) * 8192); row r at r*64;
// 16B chunk c of the 64B k-slice at slot c ^ ((r>>1)&3) (bijective in 1KB).
// ---------------------------------------------------------------------------
#define QUANT_BLOCKS M_DIM
#define DEQ_BLOCKS ((N_DIM * K_DIM) / 8 / 256)       // 8 codes / thread

__global__ __launch_bounds__(256) void prep_kernel(
        const float* __restrict__ x,
        const int* __restrict__ qw,          // [N][K] codes 0..15 as int32
        const float* __restrict__ wsc,       // [N][32]
        const int* __restrict__ wzp,         // [N][32]
        char* __restrict__ A8,               // tiled [16][64][128][64]
        char* __restrict__ Bt8,              // tiled [32][64][128][64]
        float* __restrict__ xscale,          // [M]
        float* __restrict__ xzpc,            // [M]  = 128 - zp
        int* __restrict__ Sw)                // [N][32] group sums of Bt8
{
    const int t = threadIdx.x;
    if (blockIdx.x < QUANT_BLOCKS) {
        const int s = blockIdx.x;
        const float* xrow = x + (size_t)s * K_DIM;

        float xv[16];
        float vmin = 1e38f, vmax = -1e38f;
#pragma unroll
        for (int p = 0; p < 4; ++p) {
            float4 v = *((const float4*)(xrow + p * 1024) + t);
            xv[p*4+0] = v.x; xv[p*4+1] = v.y; xv[p*4+2] = v.z; xv[p*4+3] = v.w;
            vmin = fminf(vmin, fminf(fminf(v.x, v.y), fminf(v.z, v.w)));
            vmax = fmaxf(vmax, fmaxf(fmaxf(v.x, v.y), fmaxf(v.z, v.w)));
        }
#pragma unroll
        for (int off = 32; off > 0; off >>= 1) {
            vmin = fminf(vmin, __shfl_xor(vmin, off));
            vmax = fmaxf(vmax, __shfl_xor(vmax, off));
        }
        __shared__ float smin[4], smax[4];
        const int wave = t >> 6;
        if ((t & 63) == 0) { smin[wave] = vmin; smax[wave] = vmax; }
        __syncthreads();
        vmin = fminf(fminf(smin[0], smin[1]), fminf(smin[2], smin[3]));
        vmax = fmaxf(fmaxf(smax[0], smax[1]), fmaxf(smax[2], smax[3]));

        float sc = (vmax - vmin) / 255.0f;
        sc = fmaxf(sc, 1e-5f);
        float zp = rintf(-vmin / sc);
        zp = fminf(fmaxf(zp, 0.0f), 255.0f);
        const float inv_sc = 1.0f / sc;

        const int r   = s & 127;
        const int mt  = s >> 7;
        const int swr = (r >> 1) & 3;
#pragma unroll
        for (int p = 0; p < 4; ++p) {
            int b[4];
#pragma unroll
            for (int e = 0; e < 4; ++e) {
                float q = fminf(fmaxf(rintf(xv[p*4+e] * inv_sc) + zp, 0.0f), 255.0f);
                b[e] = (int)q - 128;
            }
            unsigned pack = (b[0] & 0xff) | ((b[1] & 0xff) << 8) |
                            ((b[2] & 0xff) << 16) | ((b[3] & 0xff) << 24);
            const int kt   = p * 16 + (t >> 4);
            const int slot = ((t >> 2) & 3) ^ swr;
            *(unsigned*)(A8 + (((size_t)(mt * 64 + kt)) << 13)
                            + r * 64 + slot * 16 + (t & 3) * 4) = pack;
        }
        if (t == 0) { xscale[s] = sc; xzpc[s] = 128.0f - zp; }
    } else {
        // ---- weight requant: 8 codes/thread; 16-lane cluster = 1 group ----
        const size_t base = ((size_t)(blockIdx.x - QUANT_BLOCKS) * 256 + t) * 8;
        const int n = (int)(base >> 12);          // /4096
        const int g = (int)((base >> 7) & 31);
        const int zp = wzp[n * NGROUP + g];

        // inline rsn: row max of the 32 scales across the 16-lane cluster
        const int cl = t & 15;
        float2 wp = *(const float2*)(wsc + (size_t)n * NGROUP + cl * 2);
        float smx = fmaxf(wp.x, wp.y);
#pragma unroll
        for (int off = 1; off < 16; off <<= 1)
            smx = fmaxf(smx, __shfl_xor(smx, off));
        const float factor = wsc[n * NGROUP + g] * (RQ_UP / smx);   // <= 127/15

        int4 c0 = *(const int4*)(qw + base);
        int4 c1 = *(const int4*)(qw + base + 4);
        int w[8];
        w[0] = (int)rintf((float)(c0.x - zp) * factor);
        w[1] = (int)rintf((float)(c0.y - zp) * factor);
        w[2] = (int)rintf((float)(c0.z - zp) * factor);
        w[3] = (int)rintf((float)(c0.w - zp) * factor);
        w[4] = (int)rintf((float)(c1.x - zp) * factor);
        w[5] = (int)rintf((float)(c1.y - zp) * factor);
        w[6] = (int)rintf((float)(c1.z - zp) * factor);
        w[7] = (int)rintf((float)(c1.w - zp) * factor);
        uint2 pk;
        pk.x = (w[0] & 0xff) | ((w[1] & 0xff) << 8) | ((w[2] & 0xff) << 16) | ((w[3] & 0xff) << 24);
        pk.y = (w[4] & 0xff) | ((w[5] & 0xff) << 8) | ((w[6] & 0xff) << 16) | ((w[7] & 0xff) << 24);

        const int r  = n & 127;
        const int nt = n >> 7;
        const int kt = (int)((base >> 6) & 63);
        const int slot = (int)(((base >> 4) & 3)) ^ ((r >> 1) & 3);
        *(uint2*)(Bt8 + (((size_t)(nt * 64 + kt)) << 13)
                      + r * 64 + slot * 16 + (int)(base & 15)) = pk;

        int s8 = w[0] + w[1] + w[2] + w[3] + w[4] + w[5] + w[6] + w[7];
#pragma unroll
        for (int off = 1; off < 16; off <<= 1) s8 += __shfl_xor(s8, off);
        if ((t & 15) == 0)
            Sw[n * NGROUP + g] = s8;     // coalesced, no atomic
    }
}

// ---------------------------------------------------------------------------
// Zero-LDS i8 GEMM. No barriers / LDS / asm in the K-loop; compiler emits
// counted waitcnts for the register loads (the proven-good path).
// Epilogue: out[m][n] = xscale[m]*(fws[n]*iacc + czp[m]*WSf[n]) + bias[n]
// ---------------------------------------------------------------------------
__global__ __launch_bounds__(256, 1) void gemm_kernel(
        const char* __restrict__ A8,     // tiled [16][64][128][64]
        const char* __restrict__ Bt8,    // tiled [32][64][128][64]
        const float* __restrict__ xscale,
        const float* __restrict__ xzpc,
        const float* __restrict__ wsc,   // [N][32]
        const int* __restrict__ Sw,      // [N][32]
        const float* __restrict__ bias,  // [N]
        float* __restrict__ out)         // [M][N] f32
{
    __shared__ float fws_s[BN], wsf_s[BN];   // epilogue constants only

    const int tid  = threadIdx.x;
    const int bn   = blockIdx.x;         // 0..15 -> 256-col band (2 n-tiles)
    const int bm   = blockIdx.y;         // 0..15 -> 128-row tile
    const int wave = tid >> 6;           // 0..3
    const int lane = tid & 63;
    const int wr   = wave >> 1;          // 0..1 -> 64-row band
    const int wcl  = wave & 1;           // 0..1 -> 128-col band (one n-tile)
    const int lrow  = lane & 15;
    const int lquad = lane >> 4;         // 0..3 -> 16B k-chunk

    // --- per-column epilogue constants: thread tid owns column tid ---
    {
        const int n = bn * BN + tid;
        const int4* s4 = (const int4*)(Sw + (size_t)n * NGROUP);
        int acc = 0;
#pragma unroll
        for (int p = 0; p < 8; ++p) { int4 v = s4[p]; acc += v.x + v.y + v.z + v.w; }
        const float4* w4 = (const float4*)(wsc + (size_t)n * NGROUP);
        float s = 0.f;
#pragma unroll
        for (int p = 0; p < 8; ++p) {
            float4 w = w4[p];
            s = fmaxf(s, fmaxf(fmaxf(w.x, w.y), fmaxf(w.z, w.w)));
        }
        const float fw = s * RQ_DOWN;
        fws_s[tid] = fw;
        wsf_s[tid] = fw * (float)acc;
        // no barrier here — synced once before the epilogue
    }

    // --- per-lane fragment bases in the tiled layout. Within a 1 KiB frag
    // block, lane (lquad,lrow) reads 16B at lrow*64 + (lquad^swz(lrow))*16
    // — a bijection onto the block: 8x128B segments, perfectly coalesced.
    const int xq = (lquad ^ ((lrow >> 1) & 3)) * 16;
    const char* pA = A8 + ((size_t)bm << 19)
                        + (size_t)(wr * 64 + lrow) * 64 + xq;     // frag i: +i*1024
    const char* pB = Bt8 + ((size_t)(bn * 2 + wcl) << 19)
                        + (size_t)lrow * 64 + xq;                 // frag j: +j*1024

    int32x4_t iacc[4][8];
    const int32x4_t zi = {0, 0, 0, 0};
#pragma unroll
    for (int i = 0; i < 4; ++i)
#pragma unroll
        for (int j = 0; j < 8; ++j) iacc[i][j] = zi;

#define LOADF(s, aF, bF) {                                            \
        const char* a_ = pA + ((size_t)(s) << 13);                    \
        const char* b_ = pB + ((size_t)(s) << 13);                    \
        _Pragma("unroll")                                             \
        for (int i_ = 0; i_ < 4; ++i_)                                \
            aF[i_] = *(const int32x4_t*)(a_ + i_ * 1024);             \
        _Pragma("unroll")                                             \
        for (int j_ = 0; j_ < 8; ++j_)                                \
            bF[j_] = *(const int32x4_t*)(b_ + j_ * 1024);             \
    }

#define MFMAS(aF, bF) {                                               \
        _Pragma("unroll")                                             \
        for (int i_ = 0; i_ < 4; ++i_)                                \
            _Pragma("unroll")                                         \
            for (int j_ = 0; j_ < 8; ++j_)                            \
                iacc[i_][j_] = __builtin_amdgcn_mfma_i32_16x16x64_i8( \
                    aF[i_], bF[j_], iacc[i_][j_], 0, 0, 0);           \
    }

    int32x4_t aX[4], bX[8], aY[4], bY[8];

    // ---- software pipeline: depth-2 register double-buffer ----
    LOADF(0, aX, bX);
    LOADF(1, aY, bY);
#pragma unroll 1
    for (int s = 0; s < NSLICE - 2; s += 2) {
        MFMAS(aX, bX);           // waits on X's loads (compiler-counted)
        LOADF(s + 2, aX, bX);    // refill X while Y computes
        MFMAS(aY, bY);
        LOADF(s + 3, aY, bY);
    }
    MFMAS(aX, bX);
    MFMAS(aY, bY);

    __syncthreads();             // publish fws_s / wsf_s (only barrier)

    // --- epilogue: C/D layout col=lane&15, row=lquad*4+reg ---
    float fn[8], wf[8], bb[8];
    int ncol[8];
#pragma unroll
    for (int j = 0; j < 8; ++j) {
        const int ncl = wcl * 128 + j * 16 + lrow;
        ncol[j] = bn * BN + ncl;
        fn[j] = fws_s[ncl];
        wf[j] = wsf_s[ncl];
        bb[j] = bias[ncol[j]];
    }
    const int m0 = bm * BM + wr * 64;
#pragma unroll
    for (int i = 0; i < 4; ++i) {
#pragma unroll
        for (int r = 0; r < 4; ++r) {
            const int m = m0 + i * 16 + lquad * 4 + r;
            const float xs  = xscale[m];
            const float czp = xzpc[m];
            float* orow = out + (size_t)m * N_DIM;
#pragma unroll
            for (int j = 0; j < 8; ++j)
                orow[ncol[j]] = xs * (fn[j] * (float)iacc[i][j][r] + czp * wf[j]) + bb[j];
        }
    }
#undef MFMAS
#undef LOADF
}

extern "C" void kernel_launch(void* const* d_in, const int* in_sizes, int n_in,
                              void* d_out, int out_size, void* d_ws, size_t ws_size,
                              hipStream_t stream) {
    const float* x     = (const float*)d_in[0];
    const int*   qw    = (const int*)d_in[1];
    const float* wsc   = (const float*)d_in[2];
    const int*   wzp   = (const int*)d_in[3];
    const float* bias  = (const float*)d_in[4];
    float* out = (float*)d_out;

    // workspace layout
    char* A8  = (char*)d_ws;                                   //  8 MiB (tiled)
    char* Bt8 = A8 + (size_t)M_DIM * K_DIM;                    // 16 MiB (tiled)
    float* xscale = (float*)(Bt8 + (size_t)N_DIM * K_DIM);     //  8 KiB
    float* xzpc   = xscale + M_DIM;                            //  8 KiB
    int*   Sw     = (int*)(xzpc + M_DIM);                      // 512 KiB

    prep_kernel<<<QUANT_BLOCKS + DEQ_BLOCKS, 256, 0, stream>>>(
        x, qw, wsc, wzp, A8, Bt8, xscale, xzpc, Sw);

    dim3 grid(N_DIM / BN, M_DIM / BM);                          // 16 x 16
    gemm_kernel<<<grid, 256, 0, stream>>>(
        A8, Bt8, xscale, xzpc, wsc, Sw, bias, out);
}

// Round 10
// 166.716 us; speedup vs baseline: 1.7548x; 1.0376x over previous
//
#include <hip/hip_runtime.h>
#include <stdint.h>

#define M_DIM 2048
#define N_DIM 4096
#define K_DIM 4096
#define NGROUP 32
#define GSIZE 128

#define RQ_UP   (127.0f / 15.0f)   // weight requant gain
#define RQ_DOWN (15.0f / 127.0f)

// ---------------------------------------------------------------------------
// R10: zero-LDS GEMM with a COMPILER-PROOF register pipeline.
// R9 failed because hipcc collapsed the software dbuf (VGPR=160 vs 240+
// needed): it sank each LOADF to its consuming MFMAS -> load latency fully
// exposed (900cy HBM miss + 653cy MFMA = 1830cy/step = measured 48.8us).
// Fix: fragment loads are opaque asm (12x global_load_dwordx4, early-clobber
// outs); completion enforced ONLY by bare counted s_waitcnt vmcnt(N) pinned
// with sched_barrier(0) (rule #18). Depth-3 sets (X/Y/Z): issue->use cover
// = 2 MFMA clusters (~1300cy) > HBM-miss latency. Steady vmcnt(24).
// Geometry (R9, passed): block 128x256, 4 waves 2Mx2N, wave 64x128 = 4x8
// frags of 16x16x64 i8 MFMA; k-tiled pre-swizzled A8/Bt8 (1KiB frag blocks,
// perfectly coalesced); grid 16x16 = 1 block/CU.
// ---------------------------------------------------------------------------
#define BM 128
#define BN 256
#define NSLICE (K_DIM / 64)        // 64

typedef __attribute__((ext_vector_type(4))) int int32x4_t;

#define WAITVM_(N) asm volatile("s_waitcnt vmcnt(" #N ")")
#define WAITVM(N)                                   \
    do {                                            \
        __builtin_amdgcn_sched_barrier(0);          \
        WAITVM_(N);                                 \
        __builtin_amdgcn_sched_barrier(0);          \
    } while (0)

// ---------------------------------------------------------------------------
// Fused prep (identical to R8/R9 — verified):
//   [0, 2048): per-token activation quant -> A8 tiled, xscale, czp
//   [2048, ..): weight requant -> Bt8 tiled + group sums Sw.
// Tiled layout: tile (rt, kt) at ((rt*64 + kt) * 8192); row r at r*64;
// 16B chunk c of the 64B k-slice at slot c ^ ((r>>1)&3) (bijective in 1KB).
// ---------------------------------------------------------------------------
#define QUANT_BLOCKS M_DIM
#define DEQ_BLOCKS ((N_DIM * K_DIM) / 8 / 256)       // 8 codes / thread

__global__ __launch_bounds__(256) void prep_kernel(
        const float* __restrict__ x,
        const int* __restrict__ qw,          // [N][K] codes 0..15 as int32
        const float* __restrict__ wsc,       // [N][32]
        const int* __restrict__ wzp,         // [N][32]
        char* __restrict__ A8,               // tiled [16][64][128][64]
        char* __restrict__ Bt8,              // tiled [32][64][128][64]
        float* __restrict__ xscale,          // [M]
        float* __restrict__ xzpc,            // [M]  = 128 - zp
        int* __restrict__ Sw)                // [N][32] group sums of Bt8
{
    const int t = threadIdx.x;
    if (blockIdx.x < QUANT_BLOCKS) {
        const int s = blockIdx.x;
        const float* xrow = x + (size_t)s * K_DIM;

        float xv[16];
        float vmin = 1e38f, vmax = -1e38f;
#pragma unroll
        for (int p = 0; p < 4; ++p) {
            float4 v = *((const float4*)(xrow + p * 1024) + t);
            xv[p*4+0] = v.x; xv[p*4+1] = v.y; xv[p*4+2] = v.z; xv[p*4+3] = v.w;
            vmin = fminf(vmin, fminf(fminf(v.x, v.y), fminf(v.z, v.w)));
            vmax = fmaxf(vmax, fmaxf(fmaxf(v.x, v.y), fmaxf(v.z, v.w)));
        }
#pragma unroll
        for (int off = 32; off > 0; off >>= 1) {
            vmin = fminf(vmin, __shfl_xor(vmin, off));
            vmax = fmaxf(vmax, __shfl_xor(vmax, off));
        }
        __shared__ float smin[4], smax[4];
        const int wave = t >> 6;
        if ((t & 63) == 0) { smin[wave] = vmin; smax[wave] = vmax; }
        __syncthreads();
        vmin = fminf(fminf(smin[0], smin[1]), fminf(smin[2], smin[3]));
        vmax = fmaxf(fmaxf(smax[0], smax[1]), fmaxf(smax[2], smax[3]));

        float sc = (vmax - vmin) / 255.0f;
        sc = fmaxf(sc, 1e-5f);
        float zp = rintf(-vmin / sc);
        zp = fminf(fmaxf(zp, 0.0f), 255.0f);
        const float inv_sc = 1.0f / sc;

        const int r   = s & 127;
        const int mt  = s >> 7;
        const int swr = (r >> 1) & 3;
#pragma unroll
        for (int p = 0; p < 4; ++p) {
            int b[4];
#pragma unroll
            for (int e = 0; e < 4; ++e) {
                float q = fminf(fmaxf(rintf(xv[p*4+e] * inv_sc) + zp, 0.0f), 255.0f);
                b[e] = (int)q - 128;
            }
            unsigned pack = (b[0] & 0xff) | ((b[1] & 0xff) << 8) |
                            ((b[2] & 0xff) << 16) | ((b[3] & 0xff) << 24);
            const int kt   = p * 16 + (t >> 4);
            const int slot = ((t >> 2) & 3) ^ swr;
            *(unsigned*)(A8 + (((size_t)(mt * 64 + kt)) << 13)
                            + r * 64 + slot * 16 + (t & 3) * 4) = pack;
        }
        if (t == 0) { xscale[s] = sc; xzpc[s] = 128.0f - zp; }
    } else {
        // ---- weight requant: 8 codes/thread; 16-lane cluster = 1 group ----
        const size_t base = ((size_t)(blockIdx.x - QUANT_BLOCKS) * 256 + t) * 8;
        const int n = (int)(base >> 12);          // /4096
        const int g = (int)((base >> 7) & 31);
        const int zp = wzp[n * NGROUP + g];

        // inline rsn: row max of the 32 scales across the 16-lane cluster
        const int cl = t & 15;
        float2 wp = *(const float2*)(wsc + (size_t)n * NGROUP + cl * 2);
        float smx = fmaxf(wp.x, wp.y);
#pragma unroll
        for (int off = 1; off < 16; off <<= 1)
            smx = fmaxf(smx, __shfl_xor(smx, off));
        const float factor = wsc[n * NGROUP + g] * (RQ_UP / smx);   // <= 127/15

        int4 c0 = *(const int4*)(qw + base);
        int4 c1 = *(const int4*)(qw + base + 4);
        int w[8];
        w[0] = (int)rintf((float)(c0.x - zp) * factor);
        w[1] = (int)rintf((float)(c0.y - zp) * factor);
        w[2] = (int)rintf((float)(c0.z - zp) * factor);
        w[3] = (int)rintf((float)(c0.w - zp) * factor);
        w[4] = (int)rintf((float)(c1.x - zp) * factor);
        w[5] = (int)rintf((float)(c1.y - zp) * factor);
        w[6] = (int)rintf((float)(c1.z - zp) * factor);
        w[7] = (int)rintf((float)(c1.w - zp) * factor);
        uint2 pk;
        pk.x = (w[0] & 0xff) | ((w[1] & 0xff) << 8) | ((w[2] & 0xff) << 16) | ((w[3] & 0xff) << 24);
        pk.y = (w[4] & 0xff) | ((w[5] & 0xff) << 8) | ((w[6] & 0xff) << 16) | ((w[7] & 0xff) << 24);

        const int r  = n & 127;
        const int nt = n >> 7;
        const int kt = (int)((base >> 6) & 63);
        const int slot = (int)(((base >> 4) & 3)) ^ ((r >> 1) & 3);
        *(uint2*)(Bt8 + (((size_t)(nt * 64 + kt)) << 13)
                      + r * 64 + slot * 16 + (int)(base & 15)) = pk;

        int s8 = w[0] + w[1] + w[2] + w[3] + w[4] + w[5] + w[6] + w[7];
#pragma unroll
        for (int off = 1; off < 16; off <<= 1) s8 += __shfl_xor(s8, off);
        if ((t & 15) == 0)
            Sw[n * NGROUP + g] = s8;     // coalesced, no atomic
    }
}

// ---------------------------------------------------------------------------
// Zero-LDS i8 GEMM, compiler-proof depth-3 register pipeline.
// Epilogue: out[m][n] = xscale[m]*(fws[n]*iacc + czp[m]*WSf[n]) + bias[n]
// ---------------------------------------------------------------------------
__global__ __launch_bounds__(256, 1) void gemm_kernel(
        const char* __restrict__ A8,     // tiled [16][64][128][64]
        const char* __restrict__ Bt8,    // tiled [32][64][128][64]
        const float* __restrict__ xscale,
        const float* __restrict__ xzpc,
        const float* __restrict__ wsc,   // [N][32]
        const int* __restrict__ Sw,      // [N][32]
        const float* __restrict__ bias,  // [N]
        float* __restrict__ out)         // [M][N] f32
{
    __shared__ float fws_s[BN], wsf_s[BN];   // epilogue constants only

    const int tid  = threadIdx.x;
    const int bn   = blockIdx.x;         // 0..15 -> 256-col band (2 n-tiles)
    const int bm   = blockIdx.y;         // 0..15 -> 128-row tile
    const int wave = tid >> 6;           // 0..3
    const int lane = tid & 63;
    const int wr   = wave >> 1;          // 0..1 -> 64-row band
    const int wcl  = wave & 1;           // 0..1 -> 128-col band (one n-tile)
    const int lrow  = lane & 15;
    const int lquad = lane >> 4;         // 0..3 -> 16B k-chunk

    // --- per-column epilogue constants: thread tid owns column tid ---
    {
        const int n = bn * BN + tid;
        const int4* s4 = (const int4*)(Sw + (size_t)n * NGROUP);
        int acc = 0;
#pragma unroll
        for (int p = 0; p < 8; ++p) { int4 v = s4[p]; acc += v.x + v.y + v.z + v.w; }
        const float4* w4 = (const float4*)(wsc + (size_t)n * NGROUP);
        float s = 0.f;
#pragma unroll
        for (int p = 0; p < 8; ++p) {
            float4 w = w4[p];
            s = fmaxf(s, fmaxf(fmaxf(w.x, w.y), fmaxf(w.z, w.w)));
        }
        const float fw = s * RQ_DOWN;
        fws_s[tid] = fw;
        wsf_s[tid] = fw * (float)acc;
    }
    // clean vmcnt baseline: counted waits below assume only frag loads live
    __builtin_amdgcn_sched_barrier(0);
    asm volatile("s_waitcnt vmcnt(0) lgkmcnt(0)");
    __builtin_amdgcn_sched_barrier(0);

    // --- per-lane fragment bases (R9-verified). Within a 1 KiB frag block,
    // lane (lquad,lrow) reads 16B at lrow*64 + (lquad^swz(lrow))*16 —
    // bijection onto the block: 8x128B segments, perfectly coalesced.
    const int xq = (lquad ^ ((lrow >> 1) & 3)) * 16;
    const char* pA = A8 + ((size_t)bm << 19)
                        + (size_t)(wr * 64 + lrow) * 64 + xq;     // frag i: +i*1024
    const char* pB = Bt8 + ((size_t)(bn * 2 + wcl) << 19)
                        + (size_t)lrow * 64 + xq;                 // frag j: +j*1024

    int32x4_t iacc[4][8];
    const int32x4_t zi = {0, 0, 0, 0};
#pragma unroll
    for (int i = 0; i < 4; ++i)
#pragma unroll
        for (int j = 0; j < 8; ++j) iacc[i][j] = zi;

    // Opaque asm loads: 12x global_load_dwordx4 (4 A + 8 B frags = one
    // slice for this wave). Early-clobber outs; NO compiler-known vmem ->
    // the ONLY completion guarantee is the explicit counted WAITVM.
#define LOADF(s, aF, bF) {                                            \
        const char* a_  = pA + ((size_t)(s) << 13);                   \
        const char* b0_ = pB + ((size_t)(s) << 13);                   \
        const char* b1_ = b0_ + 4096;                                 \
        asm volatile(                                                 \
            "global_load_dwordx4 %0, %12, off\n\t"                    \
            "global_load_dwordx4 %1, %12, off offset:1024\n\t"        \
            "global_load_dwordx4 %2, %12, off offset:2048\n\t"        \
            "global_load_dwordx4 %3, %12, off offset:3072\n\t"        \
            "global_load_dwordx4 %4, %13, off\n\t"                    \
            "global_load_dwordx4 %5, %13, off offset:1024\n\t"        \
            "global_load_dwordx4 %6, %13, off offset:2048\n\t"        \
            "global_load_dwordx4 %7, %13, off offset:3072\n\t"        \
            "global_load_dwordx4 %8, %14, off\n\t"                    \
            "global_load_dwordx4 %9, %14, off offset:1024\n\t"        \
            "global_load_dwordx4 %10, %14, off offset:2048\n\t"       \
            "global_load_dwordx4 %11, %14, off offset:3072"           \
            : "=&v"(aF[0]), "=&v"(aF[1]), "=&v"(aF[2]), "=&v"(aF[3]), \
              "=&v"(bF[0]), "=&v"(bF[1]), "=&v"(bF[2]), "=&v"(bF[3]), \
              "=&v"(bF[4]), "=&v"(bF[5]), "=&v"(bF[6]), "=&v"(bF[7])  \
            : "v"(a_), "v"(b0_), "v"(b1_));                           \
    }

#define MFMAS(aF, bF) {                                               \
        _Pragma("unroll")                                             \
        for (int i_ = 0; i_ < 4; ++i_)                                \
            _Pragma("unroll")                                         \
            for (int j_ = 0; j_ < 8; ++j_)                            \
                iacc[i_][j_] = __builtin_amdgcn_mfma_i32_16x16x64_i8( \
                    aF[i_], bF[j_], iacc[i_][j_], 0, 0, 0);           \
    }

    int32x4_t aX[4], bX[8], aY[4], bY[8], aZ[4], bZ[8];

    // ---- depth-3 pipeline: 36 loads in flight, vmcnt(24) steady ----
    LOADF(0, aX, bX);
    LOADF(1, aY, bY);
    LOADF(2, aZ, bZ);
#pragma unroll 1
    for (int s = 0; s < NSLICE - 4; s += 3) {
        WAITVM(24); MFMAS(aX, bX); LOADF(s + 3, aX, bX);
        WAITVM(24); MFMAS(aY, bY); LOADF(s + 4, aY, bY);
        WAITVM(24); MFMAS(aZ, bZ); LOADF(s + 5, aZ, bZ);
    }
    // tail: slices 60..63 (60%3==0 -> X; loads 63 -> X)
    WAITVM(24); MFMAS(aX, bX); LOADF(63, aX, bX);
    WAITVM(24); MFMAS(aY, bY);           // slice 61
    WAITVM(12); MFMAS(aZ, bZ);           // slice 62
    WAITVM(0);  MFMAS(aX, bX);           // slice 63

    __syncthreads();             // publish fws_s / wsf_s (only barrier)

    // --- epilogue: C/D layout col=lane&15, row=lquad*4+reg ---
    float fn[8], wf[8], bb[8];
    int ncol[8];
#pragma unroll
    for (int j = 0; j < 8; ++j) {
        const int ncl = wcl * 128 + j * 16 + lrow;
        ncol[j] = bn * BN + ncl;
        fn[j] = fws_s[ncl];
        wf[j] = wsf_s[ncl];
        bb[j] = bias[ncol[j]];
    }
    const int m0 = bm * BM + wr * 64;
#pragma unroll
    for (int i = 0; i < 4; ++i) {
#pragma unroll
        for (int r = 0; r < 4; ++r) {
            const int m = m0 + i * 16 + lquad * 4 + r;
            const float xs  = xscale[m];
            const float czp = xzpc[m];
            float* orow = out + (size_t)m * N_DIM;
#pragma unroll
            for (int j = 0; j < 8; ++j)
                orow[ncol[j]] = xs * (fn[j] * (float)iacc[i][j][r] + czp * wf[j]) + bb[j];
        }
    }
#undef MFMAS
#undef LOADF
}

extern "C" void kernel_launch(void* const* d_in, const int* in_sizes, int n_in,
                              void* d_out, int out_size, void* d_ws, size_t ws_size,
                              hipStream_t stream) {
    const float* x     = (const float*)d_in[0];
    const int*   qw    = (const int*)d_in[1];
    const float* wsc   = (const float*)d_in[2];
    const int*   wzp   = (const int*)d_in[3];
    const float* bias  = (const float*)d_in[4];
    float* out = (float*)d_out;

    // workspace layout
    char* A8  = (char*)d_ws;                                   //  8 MiB (tiled)
    char* Bt8 = A8 + (size_t)M_DIM * K_DIM;                    // 16 MiB (tiled)
    float* xscale = (float*)(Bt8 + (size_t)N_DIM * K_DIM);     //  8 KiB
    float* xzpc   = xscale + M_DIM;                            //  8 KiB
    int*   Sw     = (int*)(xzpc + M_DIM);                      // 512 KiB

    prep_kernel<<<QUANT_BLOCKS + DEQ_BLOCKS, 256, 0, stream>>>(
        x, qw, wsc, wzp, A8, Bt8, xscale, xzpc, Sw);

    dim3 grid(N_DIM / BN, M_DIM / BM);                          // 16 x 16
    gemm_kernel<<<grid, 256, 0, stream>>>(
        A8, Bt8, xscale, xzpc, wsc, Sw, bias, out);
}